// Round 10
// baseline (3114.288 us; speedup 1.0000x reference)
//
#include <hip/hip_runtime.h>

typedef unsigned short u16;
typedef __attribute__((ext_vector_type(8))) short short8;
typedef __attribute__((ext_vector_type(4))) float f32x4;

#define NN 122880   // nodes per graph
#define EE 245760   // edges per graph
#define BB 4096     // reactions
#define HH 300      // hidden
#define LD 320      // padded feature leading dim (mult of 32)
#define NCP 384     // padded out-col count in WT slots
#define WTSL (NCP * LD)   // elements per transposed-weight slot
#define BHSZ (BB * HH)
#define GNB 16      // nodes per gather block (best measured config)

__device__ __forceinline__ float b2f(u16 s) {
  union { unsigned int u; float f; } v; v.u = ((unsigned int)s) << 16; return v.f;
}
__device__ __forceinline__ u16 f2b(float f) {
  union { float f; unsigned int u; } v; v.f = f;
  unsigned int r = v.u + 0x7FFFu + ((v.u >> 16) & 1u);
  return (u16)(r >> 16);
}

// async global->LDS, 16B per lane; LDS dest = wave-uniform base + lane*16
#define GLDS16(gp, lp) __builtin_amdgcn_global_load_lds( \
    (const __attribute__((address_space(1))) unsigned int*)(gp), \
    (__attribute__((address_space(3))) unsigned int*)(lp), 16, 0, 0)

// ---------------------------------------------------------------------------
// prep: f32 weights -> zero-padded transposed bf16 WT[slot][n(384)][k(320)],
// f32 biases -> padded f32 bias[slot][384]. Slots: 0=Wn 1=We 2..4=W1 5..7=W2
// ---------------------------------------------------------------------------
__global__ __launch_bounds__(256) void prep_kernel(
    const float* __restrict__ Wn, const float* __restrict__ We,
    const float* __restrict__ W1, const float* __restrict__ W2,
    const float* __restrict__ bn, const float* __restrict__ be,
    const float* __restrict__ b1, const float* __restrict__ b2,
    u16* __restrict__ wtAll, float* __restrict__ biasAll)
{
  int idx = blockIdx.x * 256 + threadIdx.x;
  if (idx < 8 * WTSL) {
    int slot = idx / WTSL, rem = idx % WTSL;
    int n = rem / LD, k = rem % LD;
    float v = 0.f;
    if (n < HH) {
      if (slot == 0)      { if (k < 64)  v = Wn[k * HH + n]; }
      else if (slot == 1) { if (k < 16)  v = We[k * HH + n]; }
      else if (slot < 5)  { int l = slot - 2; if (k < HH) v = W1[(l * HH + k) * HH + n]; }
      else                { int l = slot - 5; if (k < HH) v = W2[(l * HH + k) * HH + n]; }
    }
    wtAll[idx] = f2b(v);
  } else {
    int j = idx - 8 * WTSL;
    if (j < 8 * NCP) {
      int slot = j / NCP, n = j % NCP;
      float v = 0.f;
      if (n < HH) {
        const float* bp = (slot == 0) ? bn : (slot == 1) ? be
                         : (slot < 5) ? (b1 + (slot - 2) * HH) : (b2 + (slot - 5) * HH);
        v = bp[n];
      }
      biasAll[j] = v;
    }
  }
}

__global__ __launch_bounds__(256) void zero_kernel(float4* __restrict__ p, int n4) {
  int i = blockIdx.x * 256 + threadIdx.x;
  if (i < n4) p[i] = make_float4(0.f, 0.f, 0.f, 0.f);
}

// ---------------------------------------------------------------------------
// CSR build: cursor doubles as counts; scan converts in place.
// fill writes int2{edge id, src id}, dst-sorted.
// ---------------------------------------------------------------------------
__global__ __launch_bounds__(256) void count_kernel(
    const int* __restrict__ dst, int* __restrict__ cursor)
{
  int e = blockIdx.x * 256 + threadIdx.x;
  if (e < EE) atomicAdd(&cursor[dst[e]], 1);
}

__global__ __launch_bounds__(1024) void scan_kernel(
    int* __restrict__ cursor, int* __restrict__ indptr)
{
  __shared__ int sd[1024];
  const int tid = threadIdx.x;
  const int base = tid * 120;          // 1024 * 120 == NN exactly
  int s = 0;
  for (int i = 0; i < 120; ++i) s += cursor[base + i];
  sd[tid] = s;
  __syncthreads();
  for (int off = 1; off < 1024; off <<= 1) {
    int v = (tid >= off) ? sd[tid - off] : 0;
    __syncthreads();
    sd[tid] += v;
    __syncthreads();
  }
  int run = sd[tid] - s;               // exclusive prefix
  for (int i = 0; i < 120; ++i) {
    int c = cursor[base + i];
    indptr[base + i] = run;
    cursor[base + i] = run;
    run += c;
  }
  if (tid == 1023) indptr[NN] = run;   // == EE
}

__global__ __launch_bounds__(256) void fill_kernel(
    const int* __restrict__ dst, const int* __restrict__ src,
    int* __restrict__ cursor, int2* __restrict__ ess)
{
  int e = blockIdx.x * 256 + threadIdx.x;
  if (e < EE) {
    int pos = atomicAdd(&cursor[dst[e]], 1);
    ess[pos] = make_int2(e, src[e]);
  }
}

// ---------------------------------------------------------------------------
// edgeprep: remove the gather's double indirection once per graph.
// eperm[t] = eraw[ess[t].x]  (f32, dst-sorted copy, bit-identical data)
// hsrc[t]  = ess[t].y
// ---------------------------------------------------------------------------
__global__ __launch_bounds__(256) void edgeprep_kernel(
    const float* __restrict__ eraw, const int2* __restrict__ ess,
    float4* __restrict__ eperm, int* __restrict__ hsrc)
{
  int t = blockIdx.x * 256 + threadIdx.x;
  if (t < EE) {
    int2 es = ess[t];
    const float4* er = (const float4*)(eraw + (long)es.x * 16);
    float4 a = er[0], b = er[1], c = er[2], d = er[3];
    eperm[(long)t * 4 + 0] = a;
    eperm[(long)t * 4 + 1] = b;
    eperm[(long)t * 4 + 2] = c;
    eperm[(long)t * 4 + 3] = d;
    hsrc[t] = es.y;
  }
}

// ---------------------------------------------------------------------------
// MFMA GEMM v3: single-pass full-width tile 128 rows x 320 cols, 8 waves
// (512 thr, wave grid 2x4, wave = 64x80 = 4x5 MFMA 16x16x32). R9 post-mortem:
// grid.y=2 re-read each A row-block twice from HBM (157MB/GEMM of A). One
// block per row-strip reads A once -> per-GEMM HBM 235->157MB, and staging
// instrs per MFMA halve. Staging keeps R8's proven global_load_lds width=16
// into LINEAR LDS (chunk (row,q) at row*64B + q*16B). f32-A path (K=64)
// reg-stages with conversion. Fragment values and per-tile MFMA order
// unchanged -> bit-identical outputs.
// ---------------------------------------------------------------------------
__global__ __launch_bounds__(512) void gemm_kernel(
    const void* __restrict__ A, int lda, int K, int a_f32,
    const u16* __restrict__ WT, const float* __restrict__ bias,
    u16* __restrict__ C, int relu)
{
  __shared__ u16 As[128 * 32];   // 16 KB, linear
  __shared__ u16 Bs[320 * 32];   // 20 KB, linear

  const int tid = threadIdx.x;
  const int lane = tid & 63, w = tid >> 6;
  const int wm = (w >> 2) * 64, wn = (w & 3) * 80;
  const int m16 = lane & 15, q = lane >> 4;
  const long r0 = (long)blockIdx.x * 128;
  const int wavebase = tid & 0x1C0;    // wave-uniform chunk base (8 waves)

  f32x4 acc[4][5];
#pragma unroll
  for (int i = 0; i < 4; ++i)
#pragma unroll
    for (int j = 0; j < 5; ++j) acc[i][j] = (f32x4){0.f, 0.f, 0.f, 0.f};

  const int nk = K >> 5;
  const u16* Ab = (const u16*)A;

  for (int kt = 0; kt < nk; ++kt) {
    const int kg = kt << 5;
    __syncthreads();
    if (a_f32) {
      // A tile reg-staged with f32->bf16 conversion: 512 chunks, 1/thread
      int row = tid >> 2, kc = (tid & 3) << 3;
      const float* Af = (const float*)A + (r0 + row) * (long)lda + kg + kc;
      float4 v0 = *(const float4*)Af;
      float4 v1 = *(const float4*)(Af + 4);
      ushort4 p0, p1;
      p0.x = f2b(v0.x); p0.y = f2b(v0.y); p0.z = f2b(v0.z); p0.w = f2b(v0.w);
      p1.x = f2b(v1.x); p1.y = f2b(v1.y); p1.z = f2b(v1.z); p1.w = f2b(v1.w);
      *(ushort4*)&As[row * 32 + kc] = p0;
      *(ushort4*)&As[row * 32 + kc + 4] = p1;
    } else {
      // A tile: 1024 16B-chunks via global_load_lds (2 instrs/thread)
#pragma unroll
      for (int i = 0; i < 2; ++i) {
        int ci = tid + i * 512;                 // chunk = row*4 + q
        int row = ci >> 2, kc = (ci & 3) << 3;
        GLDS16(Ab + (r0 + row) * (long)lda + kg + kc,
               &As[(i * 512 + wavebase) * 8]);  // + lane*16B by HW
      }
    }
    // B tile: 1280 chunks (2 full passes + half pass for waves 0-3)
#pragma unroll
    for (int i = 0; i < 2; ++i) {
      int ci = tid + i * 512;
      int row = ci >> 2, kc = (ci & 3) << 3;
      GLDS16(WT + (long)row * LD + kg + kc,
             &Bs[(i * 512 + wavebase) * 8]);
    }
    if (tid < 256) {
      int ci = tid + 1024;
      int row = ci >> 2, kc = (ci & 3) << 3;
      GLDS16(WT + (long)row * LD + kg + kc,
             &Bs[(1024 + wavebase) * 8]);
    }
    __syncthreads();   // compiler drains vmcnt(0)+lgkmcnt(0) before s_barrier

    short8 af[4], bf[5];
#pragma unroll
    for (int t = 0; t < 4; ++t) af[t] = *(const short8*)&As[(wm + t * 16 + m16) * 32 + (q << 3)];
#pragma unroll
    for (int t = 0; t < 5; ++t) bf[t] = *(const short8*)&Bs[(wn + t * 16 + m16) * 32 + (q << 3)];
#pragma unroll
    for (int tm = 0; tm < 4; ++tm)
#pragma unroll
      for (int tn = 0; tn < 5; ++tn)
        acc[tm][tn] = __builtin_amdgcn_mfma_f32_16x16x32_bf16(af[tm], bf[tn], acc[tm][tn], 0, 0, 0);
  }

  // D row = q*4+i, col = lane&15 (m89/m91-verified C/D layout)
#pragma unroll
  for (int tn = 0; tn < 5; ++tn) {
    int c = wn + tn * 16 + m16;
    float bv = bias[c];
#pragma unroll
    for (int tm = 0; tm < 4; ++tm) {
      long rbase = r0 + wm + tm * 16 + q * 4;
#pragma unroll
      for (int i = 0; i < 4; ++i) {
        float v = acc[tm][tn][i] + bv;
        if (relu) v = v > 0.f ? v : 0.f;
        C[(rbase + i) * LD + c] = f2b(v);
      }
    }
  }
}

// ---------------------------------------------------------------------------
// gather: z[n] = h[n] + sum_{t: dst-sorted edges of n} relu(h[src]+e@We+be)
// eperm/hsrc read at LINEAR addresses; only h[src] is a dependent load.
// Thread owns one column; register accumulator; no LDS.
// ---------------------------------------------------------------------------
__global__ __launch_bounds__(320) void gather_kernel(
    const u16* __restrict__ h, const float* __restrict__ eperm,
    const int* __restrict__ hsrc,
    const u16* __restrict__ wtE, const float* __restrict__ biasE,
    const int* __restrict__ indptr, u16* __restrict__ z)
{
  const int base = blockIdx.x * GNB;
  const int c = threadIdx.x;

  float wreg[16];
  {
    uint4 w0 = *(const uint4*)(wtE + (long)c * LD);
    uint4 w1 = *(const uint4*)(wtE + (long)c * LD + 8);
    const u16* pw0 = (const u16*)&w0;
    const u16* pw1 = (const u16*)&w1;
#pragma unroll
    for (int k = 0; k < 8; ++k) { wreg[k] = b2f(pw0[k]); wreg[8 + k] = b2f(pw1[k]); }
  }
  const float bv = biasE[c];

  const int t0 = indptr[base];
  const int t1 = indptr[base + GNB];

  int g = 0;                              // current node within block
  int nxt = indptr[base + 1];             // end of current node's edge range
  float s = b2f(h[(long)base * LD + c]);  // z = h + agg, eps = 0

  for (int tb = t0; tb < t1; tb += 4) {
    // tail-clamped edge indices (duplicates are guard-skipped below)
    const int tB = (tb + 1 < t1) ? tb + 1 : t1 - 1;
    const int tC = (tb + 2 < t1) ? tb + 2 : t1 - 1;
    const int tD = (tb + 3 < t1) ? tb + 3 : t1 - 1;

    // linear loads: no dependency on any prior load
    const int sA = hsrc[tb], sB = hsrc[tB], sC = hsrc[tC], sD = hsrc[tD];
    const float* rA = eperm + (long)tb * 16;
    const float* rB = eperm + (long)tB * 16;
    const float* rC = eperm + (long)tC * 16;
    const float* rD = eperm + (long)tD * 16;
    float4 A0 = *(const float4*)rA, A1 = *(const float4*)(rA + 4),
           A2 = *(const float4*)(rA + 8), A3 = *(const float4*)(rA + 12);
    float4 B0 = *(const float4*)rB, B1 = *(const float4*)(rB + 4),
           B2 = *(const float4*)(rB + 8), B3 = *(const float4*)(rB + 12);
    float4 C0 = *(const float4*)rC, C1 = *(const float4*)(rC + 4),
           C2 = *(const float4*)(rC + 8), C3 = *(const float4*)(rC + 12);
    float4 D0 = *(const float4*)rD, D1 = *(const float4*)(rD + 4),
           D2 = *(const float4*)(rD + 8), D3 = *(const float4*)(rD + 12);
    // the single dependent load level: hsrc -> h row
    float hA = b2f(h[(long)sA * LD + c]);
    float hB = b2f(h[(long)sB * LD + c]);
    float hC = b2f(h[(long)sC * LD + c]);
    float hD = b2f(h[(long)sD * LD + c]);

    float mA = bv;
    mA += A0.x * wreg[0];  mA += A0.y * wreg[1];  mA += A0.z * wreg[2];  mA += A0.w * wreg[3];
    mA += A1.x * wreg[4];  mA += A1.y * wreg[5];  mA += A1.z * wreg[6];  mA += A1.w * wreg[7];
    mA += A2.x * wreg[8];  mA += A2.y * wreg[9];  mA += A2.z * wreg[10]; mA += A2.w * wreg[11];
    mA += A3.x * wreg[12]; mA += A3.y * wreg[13]; mA += A3.z * wreg[14]; mA += A3.w * wreg[15];
    mA += hA;
    float mB = bv;
    mB += B0.x * wreg[0];  mB += B0.y * wreg[1];  mB += B0.z * wreg[2];  mB += B0.w * wreg[3];
    mB += B1.x * wreg[4];  mB += B1.y * wreg[5];  mB += B1.z * wreg[6];  mB += B1.w * wreg[7];
    mB += B2.x * wreg[8];  mB += B2.y * wreg[9];  mB += B2.z * wreg[10]; mB += B2.w * wreg[11];
    mB += B3.x * wreg[12]; mB += B3.y * wreg[13]; mB += B3.z * wreg[14]; mB += B3.w * wreg[15];
    mB += hB;
    float mC = bv;
    mC += C0.x * wreg[0];  mC += C0.y * wreg[1];  mC += C0.z * wreg[2];  mC += C0.w * wreg[3];
    mC += C1.x * wreg[4];  mC += C1.y * wreg[5];  mC += C1.z * wreg[6];  mC += C1.w * wreg[7];
    mC += C2.x * wreg[8];  mC += C2.y * wreg[9];  mC += C2.z * wreg[10]; mC += C2.w * wreg[11];
    mC += C3.x * wreg[12]; mC += C3.y * wreg[13]; mC += C3.z * wreg[14]; mC += C3.w * wreg[15];
    mC += hC;
    float mD = bv;
    mD += D0.x * wreg[0];  mD += D0.y * wreg[1];  mD += D0.z * wreg[2];  mD += D0.w * wreg[3];
    mD += D1.x * wreg[4];  mD += D1.y * wreg[5];  mD += D1.z * wreg[6];  mD += D1.w * wreg[7];
    mD += D2.x * wreg[8];  mD += D2.y * wreg[9];  mD += D2.z * wreg[10]; mD += D2.w * wreg[11];
    mD += D3.x * wreg[12]; mD += D3.y * wreg[13]; mD += D3.z * wreg[14]; mD += D3.w * wreg[15];
    mD += hD;

#pragma unroll
    for (int j = 0; j < 4; ++j) {
      const float mj = (j == 0) ? mA : (j == 1) ? mB : (j == 2) ? mC : mD;
      const int t = tb + j;
      if (t < t1) {
        while (t >= nxt) {   // advance/flush (block-uniform branch)
          z[(long)(base + g) * LD + c] = f2b(s);
          ++g;
          s = b2f(h[(long)(base + g) * LD + c]);
          nxt = indptr[base + g + 1];
        }
        s += (mj > 0.f) ? mj : 0.f;
      }
    }
  }

  // flush the node in flight, then remaining (possibly empty) nodes as h-copy
  z[(long)(base + g) * LD + c] = f2b(s);
  for (++g; g < GNB; ++g) {
    s = b2f(h[(long)(base + g) * LD + c]);
    z[(long)(base + g) * LD + c] = f2b(s);
  }
}

// ---------------------------------------------------------------------------
// pooling: seg sorted -> block b binary-searches node range, no atomics
// ---------------------------------------------------------------------------
__global__ __launch_bounds__(320) void pool_kernel(
    const u16* __restrict__ h, const int* __restrict__ seg, float* __restrict__ acc)
{
  int b = blockIdx.x;
  int lo, hi;
  { int l = 0, r = NN; while (l < r) { int m = (l + r) >> 1; if (seg[m] < b) l = m + 1; else r = m; } lo = l; }
  { int l = lo, r = NN; while (l < r) { int m = (l + r) >> 1; if (seg[m] < b + 1) l = m + 1; else r = m; } hi = l; }
  int j = threadIdx.x;
  if (j < HH) {
    float s = 0.f;
    for (int n = lo; n < hi; ++n) s += b2f(h[(long)n * LD + j]);
    acc[(long)b * HH + j] += s;
  }
}

// out[0:BHSZ) = r - p, where r lives at out[BHSZ..) and p at out[2*BHSZ..)
__global__ __launch_bounds__(256) void combine_kernel(float* __restrict__ out) {
  int i = blockIdx.x * 256 + threadIdx.x;
  if (i < BHSZ) out[i] = out[BHSZ + i] - out[2 * BHSZ + i];
}

// ---------------------------------------------------------------------------
extern "C" void kernel_launch(void* const* d_in, const int* in_sizes, int n_in,
                              void* d_out, int out_size, void* d_ws, size_t ws_size,
                              hipStream_t stream)
{
  (void)in_sizes; (void)n_in; (void)out_size; (void)ws_size;
  const float* r_x = (const float*)d_in[0];
  const float* r_e = (const float*)d_in[1];
  const float* p_x = (const float*)d_in[2];
  const float* p_e = (const float*)d_in[3];
  const float* Wn  = (const float*)d_in[4];
  const float* bn  = (const float*)d_in[5];
  const float* We  = (const float*)d_in[6];
  const float* be  = (const float*)d_in[7];
  const float* W1  = (const float*)d_in[8];
  const float* b1  = (const float*)d_in[9];
  const float* W2  = (const float*)d_in[10];
  const float* b2  = (const float*)d_in[11];
  const int* r_src = (const int*)d_in[12];
  const int* r_dst = (const int*)d_in[13];
  const int* r_seg = (const int*)d_in[14];
  const int* p_src = (const int*)d_in[15];
  const int* p_dst = (const int*)d_in[16];
  const int* p_seg = (const int*)d_in[17];
  float* out = (float*)d_out;

  // --- workspace layout (~180 MB) ---
  char* ws = (char*)d_ws;
  size_t off = 0;
  auto take = [&](size_t bytes) -> char* {
    char* p = ws + off;
    off = (off + bytes + 255) & ~(size_t)255;
    return p;
  };
  u16*   nb0     = (u16*)  take((size_t)NN * LD * 2);       // h / t ping
  u16*   nb1     = (u16*)  take((size_t)NN * LD * 2);       // z / h pong
  u16*   wtAll   = (u16*)  take((size_t)8 * WTSL * 2);      // transposed weights
  float* biasAll = (float*)take((size_t)8 * NCP * 4);       // padded biases
  int*   indptr  = (int*)  take((size_t)(NN + 1) * 4);
  int*   cursor  = (int*)  take((size_t)NN * 4);
  int2*  ess     = (int2*) take((size_t)EE * 8);            // dst-sorted {eid,src}
  float* eperm   = (float*)take((size_t)EE * 16 * 4);       // dst-sorted edge feats (f32)
  int*   hsrc    = (int*)  take((size_t)EE * 4);            // dst-sorted src ids

  float* r_acc = out + BHSZ;       // pooled reactant sums (f32, output 1)
  float* p_acc = out + 2 * BHSZ;   // pooled product sums  (f32, output 2)

  prep_kernel<<<3852, 256, 0, stream>>>(Wn, We, W1, W2, bn, be, b1, b2, wtAll, biasAll);
  zero_kernel<<<2400, 256, 0, stream>>>((float4*)r_acc, 614400);   // r_acc + p_acc

  const float* xs[3] = { r_x, r_x + (size_t)NN * 64, p_x };
  const float* es[3] = { r_e, r_e + (size_t)EE * 16, p_e };
  const int* srcs[3] = { r_src, r_src + EE, p_src };
  const int* dsts[3] = { r_dst, r_dst + EE, p_dst };
  const int* segs[3] = { r_seg, r_seg + NN, p_seg };
  float*     accs[3] = { r_acc, r_acc, p_acc };

  for (int g = 0; g < 3; ++g) {
    // CSR by dst (reused across the 3 layers of this graph)
    zero_kernel<<<120, 256, 0, stream>>>((float4*)cursor, 30720);
    count_kernel<<<960, 256, 0, stream>>>(dsts[g], cursor);
    scan_kernel<<<1, 1024, 0, stream>>>(cursor, indptr);
    fill_kernel<<<960, 256, 0, stream>>>(dsts[g], srcs[g], cursor, ess);
    edgeprep_kernel<<<960, 256, 0, stream>>>(es[g], ess, (float4*)eperm, hsrc);

    // h = relu(x @ Wn + bn)   (f32 A, K=64)
    gemm_kernel<<<NN / 128, 512, 0, stream>>>(xs[g], 64, 64, 1,
        wtAll, biasAll, nb0, 1);

    u16* hA = nb0; u16* hB = nb1;
    for (int l = 0; l < 3; ++l) {
      gather_kernel<<<NN / GNB, 320, 0, stream>>>(hA, eperm, hsrc,
          wtAll + WTSL, biasAll + NCP, indptr, hB);
      // t = relu(z @ W1[l] + b1[l])
      gemm_kernel<<<NN / 128, 512, 0, stream>>>(hB, LD, LD, 0,
          wtAll + (2 + l) * WTSL, biasAll + (2 + l) * NCP, hA, 1);
      // h = t @ W2[l] + b2[l]  (+relu if l<2)
      gemm_kernel<<<NN / 128, 512, 0, stream>>>(hA, LD, LD, 0,
          wtAll + (5 + l) * WTSL, biasAll + (5 + l) * NCP, hB, (l < 2) ? 1 : 0);
      u16* tmp = hA; hA = hB; hB = tmp;
    }
    pool_kernel<<<BB, 320, 0, stream>>>(hA, segs[g], accs[g]);
  }
  combine_kernel<<<4800, 256, 0, stream>>>(out);
}